// Round 3
// baseline (1797.277 us; speedup 1.0000x reference)
//
#include <hip/hip_runtime.h>
#include <math.h>

#define EPSV 1e-5f

// ---------------- prep: build Wcat=[Wv | Wq'] (128x384 padded), ksum, zero stats ----
__global__ __launch_bounds__(256)
void prep_kernel(const float* __restrict__ Wv, const float* __restrict__ Wq,
                 const float* __restrict__ cb,
                 float* __restrict__ wcat, float* __restrict__ ksum,
                 float* __restrict__ stats)
{
    const long gid = (long)blockIdx.x * 256 + threadIdx.x;
    if (gid < 128L * 384) {
        const int r = (int)(gid / 384);
        const int c = (int)(gid % 384);
        float v = 0.f;
        if (c < 256)      v = Wv[r * 256 + c];
        else if (c < 283) v = Wq[(c - 256) * 128 + r];   // Wq[k][r][0]
        wcat[gid] = v;
    }
    if (gid < 1024) stats[gid] = 0.f;
    if (gid < 64) {
        float s = 0.f;
        if (gid < 27) { const float* p = cb + gid * 256; for (int c = 0; c < 256; ++c) s += p[c]; }
        else if (gid >= 32 && gid < 59) { const float* p = cb + (27 + (gid - 32)) * 256; for (int c = 0; c < 256; ++c) s += p[c]; }
        ksum[gid] = s;
    }
}

// ---------------- tiled fp32 GEMM: C[MxNC] = A[MxK] * B[KxNC], split-column output --
__global__ __launch_bounds__(256)
void gemm_tile(const float* __restrict__ A, int lda,
               const float* __restrict__ B, int ldb,
               float* __restrict__ C0, int ldc0, int nc0,
               float* __restrict__ C1, int ldc1, int nc1,
               int K)
{
    __shared__ float As[16][132];   // K-major, pad 132 breaks write conflicts
    __shared__ float Bs[16][132];
    const int tid = threadIdx.x;
    const int tx = tid & 15;
    const int ty = tid >> 4;
    const long rowBase = (long)blockIdx.y * 128;
    const int  colBase = blockIdx.x * 128;

    float acc[8][8];
    #pragma unroll
    for (int i = 0; i < 8; ++i)
        #pragma unroll
        for (int j = 0; j < 8; ++j) acc[i][j] = 0.f;

    const int ar = tid >> 2;          // 0..63
    const int ak = (tid & 3) * 4;     // 0,4,8,12
    const int bk = tid >> 5;          // 0..7
    const int bc = (tid & 31) * 4;    // 0..124

    for (int k0 = 0; k0 < K; k0 += 16) {
        #pragma unroll
        for (int p = 0; p < 2; ++p) {
            const int r = ar + p * 64;
            const float4 av = *(const float4*)(A + (rowBase + r) * lda + (k0 + ak));
            As[ak + 0][r] = av.x;
            As[ak + 1][r] = av.y;
            As[ak + 2][r] = av.z;
            As[ak + 3][r] = av.w;
        }
        #pragma unroll
        for (int p = 0; p < 2; ++p) {
            const int kk = bk + p * 8;
            *(float4*)&Bs[kk][bc] = *(const float4*)(B + (long)(k0 + kk) * ldb + (colBase + bc));
        }
        __syncthreads();
        #pragma unroll
        for (int kk = 0; kk < 16; ++kk) {
            const float4 a0 = *(const float4*)&As[kk][ty * 8];
            const float4 a1 = *(const float4*)&As[kk][ty * 8 + 4];
            const float4 b0 = *(const float4*)&Bs[kk][tx * 4];        // 256B-contig group
            const float4 b1 = *(const float4*)&Bs[kk][64 + tx * 4];
            const float a[8] = {a0.x, a0.y, a0.z, a0.w, a1.x, a1.y, a1.z, a1.w};
            const float b[8] = {b0.x, b0.y, b0.z, b0.w, b1.x, b1.y, b1.z, b1.w};
            #pragma unroll
            for (int i = 0; i < 8; ++i)
                #pragma unroll
                for (int j = 0; j < 8; ++j)
                    acc[i][j] = fmaf(a[i], b[j], acc[i][j]);
        }
        __syncthreads();
    }

    #pragma unroll
    for (int i = 0; i < 8; ++i) {
        const long r = rowBase + ty * 8 + i;
        #pragma unroll
        for (int j = 0; j < 8; ++j) {
            const int c = colBase + ((j < 4) ? (tx * 4 + j) : (64 + tx * 4 + (j - 4)));
            const float v = acc[i][j];
            if (c < nc0)               C0[r * ldc0 + c] = v;
            else if (c - nc0 < nc1)    C1[r * ldc1 + (c - nc0)] = v;
        }
    }
}

// ---------------- column stats (sum, sumsq) over t1 [N,256] ------------------------
__global__ __launch_bounds__(256)
void stats_t1(const float* __restrict__ t1, float* __restrict__ stats)
{
    const int c = threadIdx.x;
    const long r0 = (long)blockIdx.x * 256;
    float s = 0.f, s2 = 0.f;
    #pragma unroll 4
    for (int r = 0; r < 256; ++r) {
        const float v = t1[(r0 + r) * 256 + c];
        s += v; s2 += v * v;
    }
    atomicAdd(&stats[c], s);
    atomicAdd(&stats[256 + c], s2);
}

// ---------------- q_pre[n] = sum_k y[nbr[n,k], k]; accumulate scalar stats ---------
__global__ __launch_bounds__(256)
void qpre_kernel(const float* __restrict__ y, const int* __restrict__ nbr,
                 float* __restrict__ qpre, float* __restrict__ stats)
{
    __shared__ int snbr[256 * 27];
    __shared__ float red[8];
    const int tid = threadIdx.x;
    const long base = (long)blockIdx.x * 256;
    for (int j = tid; j < 256 * 27; j += 256) snbr[j] = nbr[base * 27 + j];
    __syncthreads();
    float q = 0.f;
    #pragma unroll
    for (int k = 0; k < 27; ++k) {
        const int idx = snbr[tid * 27 + k];
        q += y[(long)idx * 27 + k];
    }
    qpre[base + tid] = q;
    float s = q, s2 = q * q;
    #pragma unroll
    for (int off = 32; off > 0; off >>= 1) {
        s  += __shfl_xor(s, off);
        s2 += __shfl_xor(s2, off);
    }
    const int wid = tid >> 6;
    if ((tid & 63) == 0) { red[wid] = s; red[4 + wid] = s2; }
    __syncthreads();                                  // cross-wave partials must land
    if (tid == 0) {
        atomicAdd(&stats[512], red[0] + red[1] + red[2] + red[3]);
        atomicAdd(&stats[513], red[4] + red[5] + red[6] + red[7]);
    }
}

// ---------------- fused gather/route + GEMM2: t2 = outpre(gathered) @ Wout ---------
// One block = 32 points. Phase 1: 4 waves each gather 8 points' outpre rows into
// LDS Vs[32][260]. Phase 2: 32x256 @ 256x128 tiled GEMM with Wout chunks in LDS.
__global__ __launch_bounds__(256)
void gather_gemm2(const float* __restrict__ t1, const float* __restrict__ qpre,
                  const int* __restrict__ nbr, const float* __restrict__ cb,
                  const float* __restrict__ ksum, const float* __restrict__ stats,
                  const float* __restrict__ gv, const float* __restrict__ bvp,
                  const float* __restrict__ gq, const float* __restrict__ bq,
                  const float* __restrict__ Wout, float* __restrict__ t2,
                  float inv_n)
{
    __shared__ float Vs[32][260];   // points x channels, pad 260 (16B-aligned rows)
    __shared__ float Bs[16][132];
    const int tid  = threadIdx.x;
    const int wave = tid >> 6;      // 0..3
    const int lane = tid & 63;
    const int c4   = lane * 4;
    const long p0  = (long)blockIdx.x * 32;

    // hoisted BN affine coeffs (v: 4 channels per lane; q: scalar)
    float a[4], b[4];
    #pragma unroll
    for (int j = 0; j < 4; ++j) {
        const float mu  = stats[c4 + j] * inv_n;
        const float var = stats[256 + c4 + j] * inv_n - mu * mu;
        const float sc  = gv[c4 + j] * rsqrtf(var + EPSV);
        a[j] = sc;
        b[j] = bvp[c4 + j] - mu * sc;
    }
    const float muq  = stats[512] * inv_n;
    const float varq = stats[513] * inv_n - muq * muq;
    const float aq   = gq[0] * rsqrtf(varq + EPSV);
    const float bqc  = bq[0] - muq * aq;
    float ks0 = 0.f, ks1 = 0.f;
    if (lane < 27) { ks0 = ksum[lane]; ks1 = ksum[32 + lane]; }

    // ---- phase 1: gather 8 points per wave ----
    #pragma unroll 1
    for (int t = 0; t < 8; ++t) {
        const int plocal = wave * 8 + t;
        const long p = p0 + plocal;
        float s0 = 0.f, s1 = 0.f;
        int idx = 0;
        if (lane < 27) {
            idx = nbr[p * 27 + lane];
            const float qn = fmaxf(fmaf(qpre[idx], aq, bqc), 0.f);
            s0 = qn * ks0;
            s1 = qn * ks1;
        }
        #pragma unroll
        for (int off = 32; off > 0; off >>= 1) {
            s0 += __shfl_xor(s0, off);
            s1 += __shfl_xor(s1, off);
        }
        const float mm = fmaxf(s0, s1);
        const float e0 = __expf(s0 - mm);
        const float e1 = __expf(s1 - mm);
        const float c0 = e0 / (e0 + e1);
        const float c1 = 1.f - c0;

        float acc0[4] = {0, 0, 0, 0}, acc1[4] = {0, 0, 0, 0};
        #pragma unroll
        for (int k = 0; k < 27; ++k) {
            const int ik = __shfl(idx, k);
            const float4 tt = *(const float4*)(t1 + (long)ik * 256 + c4);
            const float4 w0 = *(const float4*)(cb + k * 256 + c4);
            const float4 w1 = *(const float4*)(cb + (27 + k) * 256 + c4);
            const float v0 = fmaxf(fmaf(tt.x, a[0], b[0]), 0.f);
            const float v1 = fmaxf(fmaf(tt.y, a[1], b[1]), 0.f);
            const float v2 = fmaxf(fmaf(tt.z, a[2], b[2]), 0.f);
            const float v3 = fmaxf(fmaf(tt.w, a[3], b[3]), 0.f);
            acc0[0] = fmaf(v0, w0.x, acc0[0]); acc0[1] = fmaf(v1, w0.y, acc0[1]);
            acc0[2] = fmaf(v2, w0.z, acc0[2]); acc0[3] = fmaf(v3, w0.w, acc0[3]);
            acc1[0] = fmaf(v0, w1.x, acc1[0]); acc1[1] = fmaf(v1, w1.y, acc1[1]);
            acc1[2] = fmaf(v2, w1.z, acc1[2]); acc1[3] = fmaf(v3, w1.w, acc1[3]);
        }
        float4 o;
        o.x = fmaf(c0, acc0[0], c1 * acc1[0]);
        o.y = fmaf(c0, acc0[1], c1 * acc1[1]);
        o.z = fmaf(c0, acc0[2], c1 * acc1[2]);
        o.w = fmaf(c0, acc0[3], c1 * acc1[3]);
        *(float4*)&Vs[plocal][c4] = o;   // conflict-free: consecutive 16B per lane
    }
    __syncthreads();

    // ---- phase 2: t2[32x128] = Vs[32x256] @ Wout[256x128] ----
    const int tx2 = tid & 31;   // 4 cols each
    const int ty2 = tid >> 5;   // 4 rows each (0..7)
    float acc[4][4];
    #pragma unroll
    for (int i = 0; i < 4; ++i)
        #pragma unroll
        for (int j = 0; j < 4; ++j) acc[i][j] = 0.f;

    for (int k0 = 0; k0 < 256; k0 += 16) {
        const int bc2 = (tid & 31) * 4;
        const int br2 = tid >> 5;   // 0..7
        *(float4*)&Bs[br2][bc2]     = *(const float4*)(Wout + (long)(k0 + br2) * 128 + bc2);
        *(float4*)&Bs[br2 + 8][bc2] = *(const float4*)(Wout + (long)(k0 + br2 + 8) * 128 + bc2);
        __syncthreads();
        #pragma unroll
        for (int kk = 0; kk < 16; ++kk) {
            const float av0 = Vs[ty2 * 4 + 0][k0 + kk];
            const float av1 = Vs[ty2 * 4 + 1][k0 + kk];
            const float av2 = Vs[ty2 * 4 + 2][k0 + kk];
            const float av3 = Vs[ty2 * 4 + 3][k0 + kk];
            const float4 bv4 = *(const float4*)&Bs[kk][tx2 * 4];
            const float aa[4] = {av0, av1, av2, av3};
            const float bb[4] = {bv4.x, bv4.y, bv4.z, bv4.w};
            #pragma unroll
            for (int i = 0; i < 4; ++i)
                #pragma unroll
                for (int j = 0; j < 4; ++j)
                    acc[i][j] = fmaf(aa[i], bb[j], acc[i][j]);
        }
        __syncthreads();
    }
    #pragma unroll
    for (int i = 0; i < 4; ++i) {
        float4 o = make_float4(acc[i][0], acc[i][1], acc[i][2], acc[i][3]);
        *(float4*)(t2 + (p0 + ty2 * 4 + i) * 128 + tx2 * 4) = o;
    }
}

// ---------------- column stats over t2 [N,128] -------------------------------------
__global__ __launch_bounds__(128)
void stats_t2(const float* __restrict__ t2, float* __restrict__ stats)
{
    const int c = threadIdx.x;
    const long r0 = (long)blockIdx.x * 128;
    float s = 0.f, s2 = 0.f;
    #pragma unroll 4
    for (int r = 0; r < 128; ++r) {
        const float v = t2[(r0 + r) * 128 + c];
        s += v; s2 += v * v;
    }
    atomicAdd(&stats[544 + c], s);
    atomicAdd(&stats[672 + c], s2);
}

// ---------------- final BN+ReLU+residual (in-place on t2 == d_out) -----------------
__global__ __launch_bounds__(256)
void final_kernel(const float* __restrict__ t2, const float* __restrict__ x,
                  const float* __restrict__ stats,
                  const float* __restrict__ go, const float* __restrict__ bo,
                  float* __restrict__ out, long total4, float inv_n)
{
    const long i = (long)blockIdx.x * 256 + threadIdx.x;
    if (i >= total4) return;
    const int c4 = (int)((i * 4) & 127);
    float a[4], b[4];
    #pragma unroll
    for (int j = 0; j < 4; ++j) {
        const float mu  = stats[544 + c4 + j] * inv_n;
        const float var = stats[672 + c4 + j] * inv_n - mu * mu;
        const float sc  = go[c4 + j] * rsqrtf(var + EPSV);
        a[j] = sc;
        b[j] = bo[c4 + j] - mu * sc;
    }
    const float4 t  = *((const float4*)t2 + i);   // in-place safe: read-then-write per thread
    const float4 xx = *((const float4*)x + i);
    float4 o;
    o.x = fmaxf(fmaf(t.x, a[0], b[0]), 0.f) + xx.x;
    o.y = fmaxf(fmaf(t.y, a[1], b[1]), 0.f) + xx.y;
    o.z = fmaxf(fmaf(t.z, a[2], b[2]), 0.f) + xx.z;
    o.w = fmaxf(fmaf(t.w, a[3], b[3]), 0.f) + xx.w;
    *((float4*)out + i) = o;
}

extern "C" void kernel_launch(void* const* d_in, const int* in_sizes, int n_in,
                              void* d_out, int out_size, void* d_ws, size_t ws_size,
                              hipStream_t stream)
{
    const float* x    = (const float*)d_in[0];
    const int*   nbr  = (const int*)d_in[1];
    const float* Wv   = (const float*)d_in[2];
    const float* gv   = (const float*)d_in[3];
    const float* bv   = (const float*)d_in[4];
    const float* Wq   = (const float*)d_in[5];
    const float* gq   = (const float*)d_in[6];
    const float* bq   = (const float*)d_in[7];
    const float* cb   = (const float*)d_in[8];
    const float* Wout = (const float*)d_in[9];
    const float* go   = (const float*)d_in[10];
    const float* bo   = (const float*)d_in[11];
    float* out = (float*)d_out;
    float* ws  = (float*)d_ws;

    const int N = in_sizes[0] / 128;
    const float inv_n = 1.f / (float)N;

    // workspace (floats): 65536 + N*256 + N + N*27  (~149 MB @ N=131072).
    // t2 lives in d_out (written by gather_gemm2, finalized in-place).
    float* wcat  = ws;                         // 128*384
    float* ksum  = ws + 49152;                 // 64
    float* stats = ws + 49216;                 // 1024
    float* t1    = ws + 65536;                 // N*256
    float* qpre  = t1 + (long)N * 256;         // N
    float* y     = qpre + N;                   // N*27
    float* t2    = out;                        // N*128 in d_out

    hipLaunchKernelGGL(prep_kernel, dim3(192), dim3(256), 0, stream,
                       Wv, Wq, cb, wcat, ksum, stats);
    // t1 = x@Wv, y = x@Wq'  (fused GEMM, 3 col-tiles over 283 padded to 384)
    hipLaunchKernelGGL(gemm_tile, dim3(3, N / 128), dim3(256), 0, stream,
                       x, 128, wcat, 384, t1, 256, 256, y, 27, 27, 128);
    hipLaunchKernelGGL(stats_t1, dim3(N / 256), dim3(256), 0, stream, t1, stats);
    hipLaunchKernelGGL(qpre_kernel, dim3(N / 256), dim3(256), 0, stream, y, nbr, qpre, stats);
    hipLaunchKernelGGL(gather_gemm2, dim3(N / 32), dim3(256), 0, stream,
                       t1, qpre, nbr, cb, ksum, stats, gv, bv, gq, bq, Wout, t2, inv_n);
    hipLaunchKernelGGL(stats_t2, dim3(N / 128), dim3(128), 0, stream, t2, stats);
    hipLaunchKernelGGL(final_kernel, dim3((unsigned)(((long)N * 128 / 4 + 255) / 256)), dim3(256), 0, stream,
                       t2, x, stats, go, bo, out, (long)N * 128 / 4, inv_n);
}

// Round 4
// 862.105 us; speedup vs baseline: 2.0848x; 2.0848x over previous
//
#include <hip/hip_runtime.h>
#include <math.h>

#define EPSV 1e-5f

// ---- bf16 helpers (round-to-nearest-even pack, bit-shift unpack) ------------------
__device__ __forceinline__ unsigned short f2bf(float f) {
    unsigned u = __float_as_uint(f);
    u += 0x7fffu + ((u >> 16) & 1u);
    return (unsigned short)(u >> 16);
}
__device__ __forceinline__ float bf2f(unsigned short h) {
    return __uint_as_float(((unsigned)h) << 16);
}

// ---------------- prep: build Wcat=[Wv | Wq'] (128x384 padded), ksum, zero stats ----
__global__ __launch_bounds__(256)
void prep_kernel(const float* __restrict__ Wv, const float* __restrict__ Wq,
                 const float* __restrict__ cb,
                 float* __restrict__ wcat, float* __restrict__ ksum,
                 float* __restrict__ stats)
{
    const long gid = (long)blockIdx.x * 256 + threadIdx.x;
    if (gid < 128L * 384) {
        const int r = (int)(gid / 384);
        const int c = (int)(gid % 384);
        float v = 0.f;
        if (c < 256)      v = Wv[r * 256 + c];
        else if (c < 283) v = Wq[(c - 256) * 128 + r];   // Wq[k][r][0]
        wcat[gid] = v;
    }
    if (gid < 1024) stats[gid] = 0.f;
    if (gid < 64) {
        float s = 0.f;
        if (gid < 27) { const float* p = cb + gid * 256; for (int c = 0; c < 256; ++c) s += p[c]; }
        else if (gid >= 32 && gid < 59) { const float* p = cb + (27 + (gid - 32)) * 256; for (int c = 0; c < 256; ++c) s += p[c]; }
        ksum[gid] = s;
    }
}

// ---------------- GEMM1: [t1b(bf16) | y(f32)] = x @ wcat ---------------------------
__global__ __launch_bounds__(256)
void gemm1_kernel(const float* __restrict__ A,              // x [N,128]
                  const float* __restrict__ B,              // wcat [128,384]
                  unsigned short* __restrict__ t1b,         // [N,256] bf16
                  float* __restrict__ y)                    // [N,27]
{
    __shared__ float As[16][132];
    __shared__ float Bs[16][132];
    const int tid = threadIdx.x;
    const int tx = tid & 15;
    const int ty = tid >> 4;
    const long rowBase = (long)blockIdx.y * 128;
    const int  colBase = blockIdx.x * 128;

    float acc[8][8];
    #pragma unroll
    for (int i = 0; i < 8; ++i)
        #pragma unroll
        for (int j = 0; j < 8; ++j) acc[i][j] = 0.f;

    const int ar = tid >> 2;          // 0..63
    const int ak = (tid & 3) * 4;     // 0,4,8,12
    const int bk = tid >> 5;          // 0..7
    const int bc = (tid & 31) * 4;    // 0..124

    for (int k0 = 0; k0 < 128; k0 += 16) {
        #pragma unroll
        for (int p = 0; p < 2; ++p) {
            const int r = ar + p * 64;
            const float4 av = *(const float4*)(A + (rowBase + r) * 128 + (k0 + ak));
            As[ak + 0][r] = av.x;
            As[ak + 1][r] = av.y;
            As[ak + 2][r] = av.z;
            As[ak + 3][r] = av.w;
        }
        #pragma unroll
        for (int p = 0; p < 2; ++p) {
            const int kk = bk + p * 8;
            *(float4*)&Bs[kk][bc] = *(const float4*)(B + (long)(k0 + kk) * 384 + (colBase + bc));
        }
        __syncthreads();
        #pragma unroll
        for (int kk = 0; kk < 16; ++kk) {
            const float4 a0 = *(const float4*)&As[kk][ty * 8];
            const float4 a1 = *(const float4*)&As[kk][ty * 8 + 4];
            const float4 b0 = *(const float4*)&Bs[kk][tx * 4];
            const float4 b1 = *(const float4*)&Bs[kk][64 + tx * 4];
            const float a[8] = {a0.x, a0.y, a0.z, a0.w, a1.x, a1.y, a1.z, a1.w};
            const float b[8] = {b0.x, b0.y, b0.z, b0.w, b1.x, b1.y, b1.z, b1.w};
            #pragma unroll
            for (int i = 0; i < 8; ++i)
                #pragma unroll
                for (int j = 0; j < 8; ++j)
                    acc[i][j] = fmaf(a[i], b[j], acc[i][j]);
        }
        __syncthreads();
    }

    if (colBase < 256) {
        // t1 region: pack 4-wide bf16 stores (8B each)
        #pragma unroll
        for (int i = 0; i < 8; ++i) {
            const long r = rowBase + ty * 8 + i;
            ushort4 u0, u1;
            u0.x = f2bf(acc[i][0]); u0.y = f2bf(acc[i][1]); u0.z = f2bf(acc[i][2]); u0.w = f2bf(acc[i][3]);
            u1.x = f2bf(acc[i][4]); u1.y = f2bf(acc[i][5]); u1.z = f2bf(acc[i][6]); u1.w = f2bf(acc[i][7]);
            *(ushort4*)(t1b + r * 256 + colBase + tx * 4)      = u0;
            *(ushort4*)(t1b + r * 256 + colBase + 64 + tx * 4) = u1;
        }
    } else {
        // y region: cols 256..282
        #pragma unroll
        for (int i = 0; i < 8; ++i) {
            const long r = rowBase + ty * 8 + i;
            #pragma unroll
            for (int j = 0; j < 8; ++j) {
                const int c = ((j < 4) ? (tx * 4 + j) : (64 + tx * 4 + (j - 4)));  // 0..127
                if (c < 27) y[r * 27 + c] = acc[i][j];
            }
        }
    }
}

// ---------------- column stats (sum, sumsq) over t1b [N,256] bf16 ------------------
__global__ __launch_bounds__(256)
void stats_t1(const unsigned short* __restrict__ t1b, float* __restrict__ stats)
{
    const int c = threadIdx.x;
    const long r0 = (long)blockIdx.x * 256;
    float s = 0.f, s2 = 0.f;
    #pragma unroll 4
    for (int r = 0; r < 256; ++r) {
        const float v = bf2f(t1b[(r0 + r) * 256 + c]);
        s += v; s2 += v * v;
    }
    atomicAdd(&stats[c], s);
    atomicAdd(&stats[256 + c], s2);
}

// ---------------- q_pre[n] = sum_k y[nbr[n,k], k]; accumulate scalar stats ---------
__global__ __launch_bounds__(256)
void qpre_kernel(const float* __restrict__ y, const int* __restrict__ nbr,
                 float* __restrict__ qpre, float* __restrict__ stats)
{
    __shared__ int snbr[256 * 27];
    __shared__ float red[8];
    const int tid = threadIdx.x;
    const long base = (long)blockIdx.x * 256;
    for (int j = tid; j < 256 * 27; j += 256) snbr[j] = nbr[base * 27 + j];
    __syncthreads();
    float q = 0.f;
    #pragma unroll
    for (int k = 0; k < 27; ++k) {
        const int idx = snbr[tid * 27 + k];
        q += y[(long)idx * 27 + k];
    }
    qpre[base + tid] = q;
    float s = q, s2 = q * q;
    #pragma unroll
    for (int off = 32; off > 0; off >>= 1) {
        s  += __shfl_xor(s, off);
        s2 += __shfl_xor(s2, off);
    }
    const int wid = tid >> 6;
    if ((tid & 63) == 0) { red[wid] = s; red[4 + wid] = s2; }
    __syncthreads();
    if (tid == 0) {
        atomicAdd(&stats[512], red[0] + red[1] + red[2] + red[3]);
        atomicAdd(&stats[513], red[4] + red[5] + red[6] + red[7]);
    }
}

// ---------------- gather/route: ONE WAVE PER POINT, no LDS -------------------------
// outpre[p] = c0 * sum_k v(nbr)⊙cb0[k] + c1 * sum_k v(nbr)⊙cb1[k], bf16 out.
__global__ __launch_bounds__(256, 4)
void gather_route(const unsigned short* __restrict__ t1b, const float* __restrict__ qpre,
                  const int* __restrict__ nbr, const float* __restrict__ cb,
                  const float* __restrict__ ksum, const float* __restrict__ stats,
                  const float* __restrict__ gv, const float* __restrict__ bvp,
                  const float* __restrict__ gq, const float* __restrict__ bq,
                  unsigned short* __restrict__ outpre, float inv_n)
{
    const long p  = (long)((blockIdx.x * 256 + threadIdx.x) >> 6);
    const int lane = threadIdx.x & 63;
    const int c4   = lane * 4;

    // per-lane v-BN affine coeffs (4 channels)
    float a[4], b[4];
    #pragma unroll
    for (int j = 0; j < 4; ++j) {
        const float mu  = stats[c4 + j] * inv_n;
        const float var = stats[256 + c4 + j] * inv_n - mu * mu;
        const float sc  = gv[c4 + j] * rsqrtf(var + EPSV);
        a[j] = sc;
        b[j] = bvp[c4 + j] - mu * sc;
    }
    // choice softmax: lanes 0..26 gather q of neighbors
    float s0 = 0.f, s1 = 0.f;
    int idx = 0;
    {
        const float muq  = stats[512] * inv_n;
        const float varq = stats[513] * inv_n - muq * muq;
        const float aq   = gq[0] * rsqrtf(varq + EPSV);
        const float bqc  = bq[0] - muq * aq;
        if (lane < 27) {
            idx = nbr[p * 27 + lane];
            const float qn = fmaxf(fmaf(qpre[idx], aq, bqc), 0.f);
            s0 = qn * ksum[lane];
            s1 = qn * ksum[32 + lane];
        }
    }
    #pragma unroll
    for (int off = 32; off > 0; off >>= 1) {
        s0 += __shfl_xor(s0, off);
        s1 += __shfl_xor(s1, off);
    }
    const float mm = fmaxf(s0, s1);
    const float e0 = __expf(s0 - mm);
    const float e1 = __expf(s1 - mm);
    const float c0 = e0 / (e0 + e1);
    const float c1 = 1.f - c0;

    float acc0[4] = {0, 0, 0, 0}, acc1[4] = {0, 0, 0, 0};
    #pragma unroll
    for (int k = 0; k < 27; ++k) {
        const int ik = __shfl(idx, k);
        const uint2 uu  = *(const uint2*)(t1b + (long)ik * 256 + c4);   // 4 bf16, 8B/lane
        const float4 w0 = *(const float4*)(cb + k * 256 + c4);
        const float4 w1 = *(const float4*)(cb + (27 + k) * 256 + c4);
        const float t0 = __uint_as_float(uu.x << 16);
        const float t1v = __uint_as_float(uu.x & 0xffff0000u);
        const float t2v = __uint_as_float(uu.y << 16);
        const float t3 = __uint_as_float(uu.y & 0xffff0000u);
        const float v0 = fmaxf(fmaf(t0,  a[0], b[0]), 0.f);
        const float v1 = fmaxf(fmaf(t1v, a[1], b[1]), 0.f);
        const float v2 = fmaxf(fmaf(t2v, a[2], b[2]), 0.f);
        const float v3 = fmaxf(fmaf(t3,  a[3], b[3]), 0.f);
        acc0[0] = fmaf(v0, w0.x, acc0[0]); acc0[1] = fmaf(v1, w0.y, acc0[1]);
        acc0[2] = fmaf(v2, w0.z, acc0[2]); acc0[3] = fmaf(v3, w0.w, acc0[3]);
        acc1[0] = fmaf(v0, w1.x, acc1[0]); acc1[1] = fmaf(v1, w1.y, acc1[1]);
        acc1[2] = fmaf(v2, w1.z, acc1[2]); acc1[3] = fmaf(v3, w1.w, acc1[3]);
    }
    ushort4 o;
    o.x = f2bf(fmaf(c0, acc0[0], c1 * acc1[0]));
    o.y = f2bf(fmaf(c0, acc0[1], c1 * acc1[1]));
    o.z = f2bf(fmaf(c0, acc0[2], c1 * acc1[2]));
    o.w = f2bf(fmaf(c0, acc0[3], c1 * acc1[3]));
    *(ushort4*)(outpre + p * 256 + c4) = o;
}

// ---------------- GEMM2: t2[N,128] = outpre[N,256](bf16) @ Wout[256,128] -----------
__global__ __launch_bounds__(256)
void gemm2_kernel(const unsigned short* __restrict__ A,
                  const float* __restrict__ B,
                  float* __restrict__ C)
{
    __shared__ float As[16][132];
    __shared__ float Bs[16][132];
    const int tid = threadIdx.x;
    const int tx = tid & 15;
    const int ty = tid >> 4;
    const long rowBase = (long)blockIdx.x * 128;

    float acc[8][8];
    #pragma unroll
    for (int i = 0; i < 8; ++i)
        #pragma unroll
        for (int j = 0; j < 8; ++j) acc[i][j] = 0.f;

    const int ar = tid >> 1;          // 0..127
    const int ak = (tid & 1) * 8;     // 0 or 8
    const int bk = tid >> 5;          // 0..7
    const int bc = (tid & 31) * 4;    // 0..124

    for (int k0 = 0; k0 < 256; k0 += 16) {
        const uint4 av = *(const uint4*)(A + (rowBase + ar) * 256 + (k0 + ak));  // 8 bf16
        As[ak + 0][ar] = __uint_as_float(av.x << 16);
        As[ak + 1][ar] = __uint_as_float(av.x & 0xffff0000u);
        As[ak + 2][ar] = __uint_as_float(av.y << 16);
        As[ak + 3][ar] = __uint_as_float(av.y & 0xffff0000u);
        As[ak + 4][ar] = __uint_as_float(av.z << 16);
        As[ak + 5][ar] = __uint_as_float(av.z & 0xffff0000u);
        As[ak + 6][ar] = __uint_as_float(av.w << 16);
        As[ak + 7][ar] = __uint_as_float(av.w & 0xffff0000u);
        #pragma unroll
        for (int q = 0; q < 2; ++q) {
            const int kk = bk + q * 8;
            *(float4*)&Bs[kk][bc] = *(const float4*)(B + (long)(k0 + kk) * 128 + bc);
        }
        __syncthreads();
        #pragma unroll
        for (int kk = 0; kk < 16; ++kk) {
            const float4 a0 = *(const float4*)&As[kk][ty * 8];
            const float4 a1 = *(const float4*)&As[kk][ty * 8 + 4];
            const float4 b0 = *(const float4*)&Bs[kk][tx * 4];
            const float4 b1 = *(const float4*)&Bs[kk][64 + tx * 4];
            const float a[8] = {a0.x, a0.y, a0.z, a0.w, a1.x, a1.y, a1.z, a1.w};
            const float b[8] = {b0.x, b0.y, b0.z, b0.w, b1.x, b1.y, b1.z, b1.w};
            #pragma unroll
            for (int i = 0; i < 8; ++i)
                #pragma unroll
                for (int j = 0; j < 8; ++j)
                    acc[i][j] = fmaf(a[i], b[j], acc[i][j]);
        }
        __syncthreads();
    }
    #pragma unroll
    for (int i = 0; i < 8; ++i) {
        const long r = rowBase + ty * 8 + i;
        float4 o0 = make_float4(acc[i][0], acc[i][1], acc[i][2], acc[i][3]);
        float4 o1 = make_float4(acc[i][4], acc[i][5], acc[i][6], acc[i][7]);
        *(float4*)(C + r * 128 + tx * 4)      = o0;
        *(float4*)(C + r * 128 + 64 + tx * 4) = o1;
    }
}

// ---------------- column stats over t2 [N,128] -------------------------------------
__global__ __launch_bounds__(128)
void stats_t2(const float* __restrict__ t2, float* __restrict__ stats)
{
    const int c = threadIdx.x;
    const long r0 = (long)blockIdx.x * 128;
    float s = 0.f, s2 = 0.f;
    #pragma unroll 4
    for (int r = 0; r < 128; ++r) {
        const float v = t2[(r0 + r) * 128 + c];
        s += v; s2 += v * v;
    }
    atomicAdd(&stats[544 + c], s);
    atomicAdd(&stats[672 + c], s2);
}

// ---------------- final BN+ReLU+residual (in-place on t2 == d_out) -----------------
__global__ __launch_bounds__(256)
void final_kernel(const float* __restrict__ t2, const float* __restrict__ x,
                  const float* __restrict__ stats,
                  const float* __restrict__ go, const float* __restrict__ bo,
                  float* __restrict__ out, long total4, float inv_n)
{
    const long i = (long)blockIdx.x * 256 + threadIdx.x;
    if (i >= total4) return;
    const int c4 = (int)((i * 4) & 127);
    float a[4], b[4];
    #pragma unroll
    for (int j = 0; j < 4; ++j) {
        const float mu  = stats[544 + c4 + j] * inv_n;
        const float var = stats[672 + c4 + j] * inv_n - mu * mu;
        const float sc  = go[c4 + j] * rsqrtf(var + EPSV);
        a[j] = sc;
        b[j] = bo[c4 + j] - mu * sc;
    }
    const float4 t  = *((const float4*)t2 + i);   // in-place safe
    const float4 xx = *((const float4*)x + i);
    float4 o;
    o.x = fmaxf(fmaf(t.x, a[0], b[0]), 0.f) + xx.x;
    o.y = fmaxf(fmaf(t.y, a[1], b[1]), 0.f) + xx.y;
    o.z = fmaxf(fmaf(t.z, a[2], b[2]), 0.f) + xx.z;
    o.w = fmaxf(fmaf(t.w, a[3], b[3]), 0.f) + xx.w;
    *((float4*)out + i) = o;
}

extern "C" void kernel_launch(void* const* d_in, const int* in_sizes, int n_in,
                              void* d_out, int out_size, void* d_ws, size_t ws_size,
                              hipStream_t stream)
{
    const float* x    = (const float*)d_in[0];
    const int*   nbr  = (const int*)d_in[1];
    const float* Wv   = (const float*)d_in[2];
    const float* gv   = (const float*)d_in[3];
    const float* bv   = (const float*)d_in[4];
    const float* Wq   = (const float*)d_in[5];
    const float* gq   = (const float*)d_in[6];
    const float* bq   = (const float*)d_in[7];
    const float* cb   = (const float*)d_in[8];
    const float* Wout = (const float*)d_in[9];
    const float* go   = (const float*)d_in[10];
    const float* bo   = (const float*)d_in[11];
    float* out = (float*)d_out;
    float* ws  = (float*)d_ws;

    const int N = in_sizes[0] / 128;
    const float inv_n = 1.f / (float)N;

    // workspace (floats): 65536 + N*(128 + 27 + 1 + 128)  (~149 MB @ N=131072)
    float* wcat  = ws;                                     // 128*384
    float* ksum  = ws + 49152;                             // 64
    float* stats = ws + 49216;                             // 1024
    unsigned short* t1b = (unsigned short*)(ws + 65536);   // N*256 bf16
    float* y    = ws + 65536 + (long)N * 128;              // N*27
    float* qpre = y + (long)N * 27;                        // N
    unsigned short* outpre = (unsigned short*)(qpre + N);  // N*256 bf16
    float* t2   = out;                                     // N*128 in d_out

    hipLaunchKernelGGL(prep_kernel, dim3(192), dim3(256), 0, stream,
                       Wv, Wq, cb, wcat, ksum, stats);
    hipLaunchKernelGGL(gemm1_kernel, dim3(3, N / 128), dim3(256), 0, stream,
                       x, wcat, t1b, y);
    hipLaunchKernelGGL(stats_t1, dim3(N / 256), dim3(256), 0, stream, t1b, stats);
    hipLaunchKernelGGL(qpre_kernel, dim3(N / 256), dim3(256), 0, stream, y, nbr, qpre, stats);
    hipLaunchKernelGGL(gather_route, dim3(N / 4), dim3(256), 0, stream,
                       t1b, qpre, nbr, cb, ksum, stats, gv, bv, gq, bq, outpre, inv_n);
    hipLaunchKernelGGL(gemm2_kernel, dim3(N / 128), dim3(256), 0, stream,
                       outpre, Wout, t2);
    hipLaunchKernelGGL(stats_t2, dim3(N / 128), dim3(128), 0, stream, t2, stats);
    hipLaunchKernelGGL(final_kernel, dim3((unsigned)(((long)N * 128 / 4 + 255) / 256)), dim3(256), 0, stream,
                       t2, x, stats, go, bo, out, (long)N * 128 / 4, inv_n);
}